// Round 17
// baseline (182.022 us; speedup 1.0000x reference)
//
#include <hip/hip_runtime.h>
#include <math.h>

#define N_NODES 50000
#define N_EDGES 1600000
#define NFEAT 256
#define NHID 64
#define NCLASS 16

#define PBITS 7
#define PNODES 128                       // nodes per bin (R5-proven geometry)
#define NBINS ((N_NODES + PNODES - 1) / PNODES)   // 391
#define BIN_CAP 5120                     // mean 4092, sigma 64 -> +16 sigma
#define K3_CHUNK 4096
#define K3_THREADS 512
#define K3_PER_T 8                       // 4096 / 512
#define K3_BLOCKS ((N_EDGES + K3_CHUNK - 1) / K3_CHUNK)  // 391
#define S_PER_T 5                        // ceil(BIN_CAP / 1024)

typedef __attribute__((ext_vector_type(8))) short bf16x8;
typedef __attribute__((ext_vector_type(4))) float f32x4;

__device__ inline unsigned short f2bf(float f) {     // RNE f32 -> bf16
    unsigned u = __float_as_uint(f);
    return (unsigned short)((u + 0x7FFFu + ((u >> 16) & 1u)) >> 16);
}

// ======================= bin scatter (counting sort, pass 1) ===============
// R10-proven 512-thread version. bin_cursor is COUNT-ONLY (zeroed by
// gemm1 block 0, which runs in the PRECEDING dispatch); slot base is
// b*BIN_CAP.
__global__ __launch_bounds__(512) void bin_scatter_kernel(
        const int* __restrict__ src, const int* __restrict__ dst,
        const float* __restrict__ w, int* __restrict__ bin_cursor,
        int2* __restrict__ csr_bin) {
    __shared__ int2 sdata[K3_CHUNK];                 // 32 KB
    __shared__ unsigned short sbinid[K3_CHUNK];      // 8 KB
    __shared__ int swhist[4][NBINS];                 // 6.1 KB (wave-pair priv)
    __shared__ int swcur[4][NBINS];                  // 6.1 KB
    __shared__ int stot[NBINS];
    __shared__ int lscan[NBINS];
    __shared__ int sbase[NBINS];
    __shared__ int stmp[512];
    int t = threadIdx.x;
    int wv = t >> 7;                                 // 4 hist copies, 2 waves ea
    int base_e = blockIdx.x * K3_CHUNK;

    for (int b = t; b < NBINS; b += K3_THREADS) {
        swhist[0][b] = 0; swhist[1][b] = 0; swhist[2][b] = 0; swhist[3][b] = 0;
    }
    __syncthreads();

    int2 myedge[K3_PER_T];
    short mybin[K3_PER_T];
#pragma unroll
    for (int k = 0; k < K3_PER_T; ++k) {
        int e = base_e + t + k * K3_THREADS;
        if (e < N_EDGES) {
            int d = min(max(dst[e], 0), N_NODES - 1);
            int s = min(max(src[e], 0), N_NODES - 1);
            int b = d >> PBITS;
            mybin[k] = (short)b;
            myedge[k] = make_int2((s << PBITS) | (d & (PNODES - 1)),
                                  __float_as_int(w[e]));
            atomicAdd(&swhist[wv][b], 1);
        } else mybin[k] = -1;
    }
    __syncthreads();
    {
        int v = 0;
        if (t < NBINS) {
            v = swhist[0][t] + swhist[1][t] + swhist[2][t] + swhist[3][t];
            stot[t] = v;
        }
        stmp[t] = v;
    }
    __syncthreads();
    for (int off = 1; off < 512; off <<= 1) {
        int v0 = (t >= off) ? stmp[t - off] : 0;
        __syncthreads();
        stmp[t] += v0;
        __syncthreads();
    }
    if (t < NBINS) {
        lscan[t] = stmp[t] - stot[t];
        int c = stot[t];
        // count-only cursor: global slot base is b*BIN_CAP + prior count
        if (c > 0) sbase[t] = t * BIN_CAP + atomicAdd(&bin_cursor[t], c);
        int run = lscan[t];
        swcur[0][t] = run; run += swhist[0][t];
        swcur[1][t] = run; run += swhist[1][t];
        swcur[2][t] = run; run += swhist[2][t];
        swcur[3][t] = run;
    }
    __syncthreads();
#pragma unroll
    for (int k = 0; k < K3_PER_T; ++k) {
        int b = mybin[k];
        if (b >= 0) {
            int p = atomicAdd(&swcur[wv][b], 1);
            sdata[p] = myedge[k];
            sbinid[p] = (unsigned short)b;
        }
    }
    __syncthreads();
    int cnt = min(N_EDGES - base_e, K3_CHUNK);
#pragma unroll
    for (int k = 0; k < K3_PER_T; ++k) {
        int p = t + k * K3_THREADS;
        if (p < cnt) {
            int b = sbinid[p];
            int idx = sbase[b] + (p - lscan[b]);
            idx = min(idx, (b + 1) * BIN_CAP - 1);   // overflow-safe (no fault)
            csr_bin[idx] = sdata[p];
        }
    }
}

// ======================= dense GEMM 1 — MFMA (R14-proven) ==================
__global__ __launch_bounds__(256) void gemm1_mfma(
        const float* __restrict__ x, const float* __restrict__ W1,
        unsigned short* __restrict__ s1b, int* __restrict__ bin_cursor) {
    __shared__ unsigned short w1t[64][264];          // W1^T bf16, 33.8 KB
    int t = threadIdx.x;
    if (blockIdx.x == 0)
        for (int i = t; i < NBINS; i += 256) bin_cursor[i] = 0;
    for (int i = t; i < NFEAT * NHID; i += 256) {    // stage W1^T
        int k = i >> 6, c = i & 63;
        w1t[c][k] = f2bf(W1[(size_t)k * NHID + c]);
    }
    __syncthreads();

    int wave = t >> 6, lane = t & 63;
    int m  = lane & 15;                              // A row / B col / D col
    int kg = lane >> 4;                              // k-group 0..3
    int arow = blockIdx.x * 64 + wave * 16 + m;
    const float* xrow = x + (size_t)min(arow, N_NODES - 1) * NFEAT;

    f32x4 ac0 = {0.f,0.f,0.f,0.f}, ac1 = {0.f,0.f,0.f,0.f};
    f32x4 ac2 = {0.f,0.f,0.f,0.f}, ac3 = {0.f,0.f,0.f,0.f};
#pragma unroll
    for (int k0 = 0; k0 < NFEAT; k0 += 32) {
        float4 xa = *(const float4*)(xrow + k0 + 8 * kg);
        float4 xb = *(const float4*)(xrow + k0 + 8 * kg + 4);
        bf16x8 af;
        af[0] = (short)f2bf(xa.x); af[1] = (short)f2bf(xa.y);
        af[2] = (short)f2bf(xa.z); af[3] = (short)f2bf(xa.w);
        af[4] = (short)f2bf(xb.x); af[5] = (short)f2bf(xb.y);
        af[6] = (short)f2bf(xb.z); af[7] = (short)f2bf(xb.w);
        bf16x8 b0 = *(const bf16x8*)&w1t[m +  0][k0 + 8 * kg];
        bf16x8 b1 = *(const bf16x8*)&w1t[m + 16][k0 + 8 * kg];
        bf16x8 b2 = *(const bf16x8*)&w1t[m + 32][k0 + 8 * kg];
        bf16x8 b3 = *(const bf16x8*)&w1t[m + 48][k0 + 8 * kg];
        ac0 = __builtin_amdgcn_mfma_f32_16x16x32_bf16(af, b0, ac0, 0, 0, 0);
        ac1 = __builtin_amdgcn_mfma_f32_16x16x32_bf16(af, b1, ac1, 0, 0, 0);
        ac2 = __builtin_amdgcn_mfma_f32_16x16x32_bf16(af, b2, ac2, 0, 0, 0);
        ac3 = __builtin_amdgcn_mfma_f32_16x16x32_bf16(af, b3, ac3, 0, 0, 0);
    }
    // D(lane, r) = tile[row = 4*kg + r][col = m]
    int obase = blockIdx.x * 64 + wave * 16 + 4 * kg;
#pragma unroll
    for (int r = 0; r < 4; ++r) {
        int n = obase + r;
        if (n < N_NODES) {
            unsigned short* op = &s1b[(size_t)n * NHID];
            op[m]      = f2bf(ac0[r]);
            op[m + 16] = f2bf(ac1[r]);
            op[m + 32] = f2bf(ac2[r]);
            op[m + 48] = f2bf(ac3[r]);
        }
    }
}

// ============ fused per-bin sort + SpMM1 + bias/ReLU + GEMM2 ===============
// R15-proven: 8 lanes/node x uint4 gathers, one round; GEMM2 in registers
// with shfl butterfly; W2s stride-17 pad.
__global__ __launch_bounds__(1024, 8) void sort_spmm1_fused(
        const int* __restrict__ bin_cursor, const int2* __restrict__ csr_bin,
        int2* __restrict__ csr_edge, int2* __restrict__ row_range,
        const uint4* __restrict__ s1p4, const float* __restrict__ b1,
        const float* __restrict__ W2, float* __restrict__ s2) {
    __shared__ int2 sdata[BIN_CAP];                  // 40 KB sorted edges
    __shared__ struct { int whist[16][PNODES]; int wcur[16][PNODES]; } c; // 16 KB
    __shared__ int ltot[PNODES];
    __shared__ int ltmp[PNODES];
    __shared__ float W2s[NHID * 17];                 // 4.25 KB, stride-17 pad
    __shared__ float b1s[NHID];
    int t = threadIdx.x;
    int wv = t >> 6;                                 // 16 waves
    int b = blockIdx.x;
    int base = b * BIN_CAP;
    int cnt = min(bin_cursor[b], BIN_CAP);

    for (int i = t; i < 16 * PNODES; i += 1024) ((int*)c.whist)[i] = 0;
    if (t < NHID * NCLASS) {
        int k = t >> 4, cc = t & 15;
        W2s[k * 17 + cc] = W2[t];
    }
    if (t < NHID) b1s[t] = b1[t];
    __syncthreads();

    // --- hist pass: load each thread's edges ONCE, keep in registers ---
    int2 myed[S_PER_T];
#pragma unroll
    for (int k = 0; k < S_PER_T; ++k) {
        int j = t + k * 1024;
        if (j < cnt) {
            int2 e0 = csr_bin[base + j];
            myed[k] = e0;
            atomicAdd(&c.whist[wv][e0.x & (PNODES - 1)], 1);
        }
    }
    __syncthreads();
    if (t < PNODES) {
        int v = 0;
#pragma unroll
        for (int k = 0; k < 16; ++k) v += c.whist[k][t];
        ltot[t] = v; ltmp[t] = v;
    }
    __syncthreads();
    for (int off = 1; off < PNODES; off <<= 1) {
        int a = 0;
        if (t < PNODES && t >= off) a = ltmp[t - off];
        __syncthreads();
        if (t < PNODES) ltmp[t] += a;
        __syncthreads();
    }
    if (t < PNODES) {
        int begl = ltmp[t] - ltot[t];                // local (0-based in bin)
        int node = b * PNODES + t;
        if (node < N_NODES)
            row_range[node] = make_int2(base + begl, base + ltmp[t]);
        int run = begl;
#pragma unroll
        for (int k = 0; k < 16; ++k) { c.wcur[k][t] = run; run += c.whist[k][t]; }
    }
    __syncthreads();
    // --- scatter pass: sorted (src, w) into LDS, from registers ---
#pragma unroll
    for (int k = 0; k < S_PER_T; ++k) {
        int j = t + k * 1024;
        if (j < cnt) {
            int2 e0 = myed[k];
            int p0 = atomicAdd(&c.wcur[wv][e0.x & (PNODES - 1)], 1);
            sdata[p0] = make_int2(e0.x >> PBITS, e0.y);
        }
    }
    __syncthreads();
    // --- coalesced writeback for spmm2 ---
    for (int i = t; i < cnt; i += 1024) csr_edge[base + i] = sdata[i];

    // --- spmm1: 128 groups x 8 lanes, uint4 gathers, one round ---
    int g = t >> 3, sub = t & 7;
    int node = b * PNODES + g;
    if (node >= N_NODES) return;
    int endl = ltmp[g];
    int j = endl - ltot[g];
    float accA[8] = {}, accB[8] = {};
    for (; j + 3 < endl; j += 4) {
        int2 e0 = sdata[j],     e1 = sdata[j + 1];
        int2 e2 = sdata[j + 2], e3 = sdata[j + 3];
        uint4 v0 = s1p4[(size_t)e0.x * 8 + sub];
        uint4 v1 = s1p4[(size_t)e1.x * 8 + sub];
        uint4 v2 = s1p4[(size_t)e2.x * 8 + sub];
        uint4 v3 = s1p4[(size_t)e3.x * 8 + sub];
        float w0 = __int_as_float(e0.y), w1 = __int_as_float(e1.y);
        float w2 = __int_as_float(e2.y), w3 = __int_as_float(e3.y);
        accA[0] = fmaf(w0, __uint_as_float(v0.x << 16), accA[0]);
        accA[1] = fmaf(w0, __uint_as_float(v0.x & 0xFFFF0000u), accA[1]);
        accA[2] = fmaf(w0, __uint_as_float(v0.y << 16), accA[2]);
        accA[3] = fmaf(w0, __uint_as_float(v0.y & 0xFFFF0000u), accA[3]);
        accA[4] = fmaf(w0, __uint_as_float(v0.z << 16), accA[4]);
        accA[5] = fmaf(w0, __uint_as_float(v0.z & 0xFFFF0000u), accA[5]);
        accA[6] = fmaf(w0, __uint_as_float(v0.w << 16), accA[6]);
        accA[7] = fmaf(w0, __uint_as_float(v0.w & 0xFFFF0000u), accA[7]);
        accB[0] = fmaf(w1, __uint_as_float(v1.x << 16), accB[0]);
        accB[1] = fmaf(w1, __uint_as_float(v1.x & 0xFFFF0000u), accB[1]);
        accB[2] = fmaf(w1, __uint_as_float(v1.y << 16), accB[2]);
        accB[3] = fmaf(w1, __uint_as_float(v1.y & 0xFFFF0000u), accB[3]);
        accB[4] = fmaf(w1, __uint_as_float(v1.z << 16), accB[4]);
        accB[5] = fmaf(w1, __uint_as_float(v1.z & 0xFFFF0000u), accB[5]);
        accB[6] = fmaf(w1, __uint_as_float(v1.w << 16), accB[6]);
        accB[7] = fmaf(w1, __uint_as_float(v1.w & 0xFFFF0000u), accB[7]);
        accA[0] = fmaf(w2, __uint_as_float(v2.x << 16), accA[0]);
        accA[1] = fmaf(w2, __uint_as_float(v2.x & 0xFFFF0000u), accA[1]);
        accA[2] = fmaf(w2, __uint_as_float(v2.y << 16), accA[2]);
        accA[3] = fmaf(w2, __uint_as_float(v2.y & 0xFFFF0000u), accA[3]);
        accA[4] = fmaf(w2, __uint_as_float(v2.z << 16), accA[4]);
        accA[5] = fmaf(w2, __uint_as_float(v2.z & 0xFFFF0000u), accA[5]);
        accA[6] = fmaf(w2, __uint_as_float(v2.w << 16), accA[6]);
        accA[7] = fmaf(w2, __uint_as_float(v2.w & 0xFFFF0000u), accA[7]);
        accB[0] = fmaf(w3, __uint_as_float(v3.x << 16), accB[0]);
        accB[1] = fmaf(w3, __uint_as_float(v3.x & 0xFFFF0000u), accB[1]);
        accB[2] = fmaf(w3, __uint_as_float(v3.y << 16), accB[2]);
        accB[3] = fmaf(w3, __uint_as_float(v3.y & 0xFFFF0000u), accB[3]);
        accB[4] = fmaf(w3, __uint_as_float(v3.z << 16), accB[4]);
        accB[5] = fmaf(w3, __uint_as_float(v3.z & 0xFFFF0000u), accB[5]);
        accB[6] = fmaf(w3, __uint_as_float(v3.w << 16), accB[6]);
        accB[7] = fmaf(w3, __uint_as_float(v3.w & 0xFFFF0000u), accB[7]);
    }
    for (; j < endl; ++j) {
        int2 e0 = sdata[j];
        uint4 v0 = s1p4[(size_t)e0.x * 8 + sub];
        float w0 = __int_as_float(e0.y);
        accA[0] = fmaf(w0, __uint_as_float(v0.x << 16), accA[0]);
        accA[1] = fmaf(w0, __uint_as_float(v0.x & 0xFFFF0000u), accA[1]);
        accA[2] = fmaf(w0, __uint_as_float(v0.y << 16), accA[2]);
        accA[3] = fmaf(w0, __uint_as_float(v0.y & 0xFFFF0000u), accA[3]);
        accA[4] = fmaf(w0, __uint_as_float(v0.z << 16), accA[4]);
        accA[5] = fmaf(w0, __uint_as_float(v0.z & 0xFFFF0000u), accA[5]);
        accA[6] = fmaf(w0, __uint_as_float(v0.w << 16), accA[6]);
        accA[7] = fmaf(w0, __uint_as_float(v0.w & 0xFFFF0000u), accA[7]);
    }
    // bias + ReLU in registers (lane sub owns cols 8*sub .. 8*sub+7)
    float h[8];
#pragma unroll
    for (int i = 0; i < 8; ++i) {
        float hv = accA[i] + accB[i] + b1s[8 * sub + i];
        h[i] = hv > 0.f ? hv : 0.f;
    }
    // gemm2 partials: 16 classes per lane over its 8 k's
    float cls[16] = {};
#pragma unroll
    for (int i = 0; i < 8; ++i)
#pragma unroll
        for (int cc = 0; cc < 16; ++cc)
            cls[cc] = fmaf(h[i], W2s[(8 * sub + i) * 17 + cc], cls[cc]);
    // butterfly reduce across the 8-lane group
#pragma unroll
    for (int off = 1; off <= 4; off <<= 1)
#pragma unroll
        for (int cc = 0; cc < 16; ++cc)
            cls[cc] += __shfl_xor(cls[cc], off, 8);
    // lane sub writes classes 2*sub, 2*sub+1 (compile-time select, no scratch)
    float o0 = 0.f, o1 = 0.f;
#pragma unroll
    for (int cc = 0; cc < 8; ++cc)
        if (sub == cc) { o0 = cls[2 * cc]; o1 = cls[2 * cc + 1]; }
    *(float2*)&s2[(size_t)node * NCLASS + 2 * sub] = make_float2(o0, o1);
}

// ======================= SpMM2 + bias + log_softmax ========================
// R16: ONE lane per edge (16 edges in flight per group). Per lane per 16
// edges: 1 coalesced csr_edge load + 4 float4 s2 loads (vs R13's 4+4) ->
// 37% fewer VMEM issues, zero redundancy. cls[16] register accumulator;
// reduce-scatter (4 halving steps, compile-time indices + shfl_xor of the
// DISCARDED half) leaves lane l holding class l; then standard 16-lane
// shfl softmax and one coalesced scalar store per lane.
__global__ void spmm2_csr_kernel(const int2* __restrict__ row_range,
                                 const int2* __restrict__ csr_edge,
                                 const float* __restrict__ s2,
                                 const float* __restrict__ b2,
                                 float* __restrict__ out) {
    int node = blockIdx.x * 16 + (threadIdx.x >> 4);
    if (node >= N_NODES) return;
    int l = threadIdx.x & 15;
    int2 rr = row_range[node];
    float cls[16] = {};
    for (int j = rr.x + l; j < rr.y; j += 16) {
        int2 e = csr_edge[j];
        const float* sp = &s2[(size_t)e.x * NCLASS];
        float4 a = *(const float4*)(sp);
        float4 bq = *(const float4*)(sp + 4);
        float4 cq = *(const float4*)(sp + 8);
        float4 dq = *(const float4*)(sp + 12);
        float w = __int_as_float(e.y);
        cls[0]  = fmaf(w, a.x,  cls[0]);
        cls[1]  = fmaf(w, a.y,  cls[1]);
        cls[2]  = fmaf(w, a.z,  cls[2]);
        cls[3]  = fmaf(w, a.w,  cls[3]);
        cls[4]  = fmaf(w, bq.x, cls[4]);
        cls[5]  = fmaf(w, bq.y, cls[5]);
        cls[6]  = fmaf(w, bq.z, cls[6]);
        cls[7]  = fmaf(w, bq.w, cls[7]);
        cls[8]  = fmaf(w, cq.x, cls[8]);
        cls[9]  = fmaf(w, cq.y, cls[9]);
        cls[10] = fmaf(w, cq.z, cls[10]);
        cls[11] = fmaf(w, cq.w, cls[11]);
        cls[12] = fmaf(w, dq.x, cls[12]);
        cls[13] = fmaf(w, dq.y, cls[13]);
        cls[14] = fmaf(w, dq.z, cls[14]);
        cls[15] = fmaf(w, dq.w, cls[15]);
    }
    // reduce-scatter: keep own half, send discarded half; lane l ends with
    // the full sum for class l. All indices compile-time (rule #20).
    float k8[8];
#pragma unroll
    for (int i = 0; i < 8; ++i) {
        float kept = (l & 8) ? cls[i + 8] : cls[i];
        float disc = (l & 8) ? cls[i]     : cls[i + 8];
        k8[i] = kept + __shfl_xor(disc, 8, 16);
    }
    float k4[4];
#pragma unroll
    for (int i = 0; i < 4; ++i) {
        float kept = (l & 4) ? k8[i + 4] : k8[i];
        float disc = (l & 4) ? k8[i]     : k8[i + 4];
        k4[i] = kept + __shfl_xor(disc, 4, 16);
    }
    float k2[2];
#pragma unroll
    for (int i = 0; i < 2; ++i) {
        float kept = (l & 2) ? k4[i + 2] : k4[i];
        float disc = (l & 2) ? k4[i]     : k4[i + 2];
        k2[i] = kept + __shfl_xor(disc, 2, 16);
    }
    float kept = (l & 1) ? k2[1] : k2[0];
    float disc = (l & 1) ? k2[0] : k2[1];
    float v = kept + __shfl_xor(disc, 1, 16);
    v += b2[l];
    // log_softmax across the 16 lanes (one class per lane)
    float mx = v;
    for (int off = 8; off; off >>= 1) mx = fmaxf(mx, __shfl_xor(mx, off, 16));
    float ss = expf(v - mx);
    for (int off = 8; off; off >>= 1) ss += __shfl_xor(ss, off, 16);
    out[(size_t)node * NCLASS + l] = v - mx - logf(ss);
}

// ======================= fallback path (R3 atomic version) =================

__global__ void zero_kernel(float* __restrict__ h, float* __restrict__ out) {
    int i = blockIdx.x * 256 + threadIdx.x;
    if (i < N_NODES * NHID) h[i] = 0.f;
    if (i < N_NODES * NCLASS) out[i] = 0.f;
}

__global__ void gemm1_kernel(const float* __restrict__ x,
                             const float* __restrict__ W1,
                             float* __restrict__ s1) {
    int node = blockIdx.x * 4 + (threadIdx.x >> 6);
    int col  = threadIdx.x & 63;
    if (node >= N_NODES) return;
    const float* xr = x + (size_t)node * NFEAT;
    float sum = 0.f;
#pragma unroll 8
    for (int k = 0; k < NFEAT; ++k)
        sum = fmaf(xr[k], W1[k * NHID + col], sum);
    s1[(size_t)node * NHID + col] = sum;
}

__global__ void spmm1_kernel(const int* __restrict__ src, const int* __restrict__ dst,
                             const float* __restrict__ w, const float* __restrict__ s1,
                             float* __restrict__ h) {
    int e = blockIdx.x * 4 + (threadIdx.x >> 6);
    if (e >= N_EDGES) return;
    int lane = threadIdx.x & 63;
    int s = min(max(src[e], 0), N_NODES - 1);
    int d = min(max(dst[e], 0), N_NODES - 1);
    float v = w[e] * s1[(size_t)s * NHID + lane];
    atomicAdd(&h[(size_t)d * NHID + lane], v);
}

__global__ void bias_relu_kernel(float* __restrict__ h, const float* __restrict__ b1) {
    int i = blockIdx.x * 256 + threadIdx.x;
    if (i >= N_NODES * NHID) return;
    float v = h[i] + b1[i & (NHID - 1)];
    h[i] = v > 0.f ? v : 0.f;
}

__global__ void gemm2_kernel(const float* __restrict__ h,
                             const float* __restrict__ W2,
                             float* __restrict__ s2) {
    int node = blockIdx.x * 16 + (threadIdx.x >> 4);
    int col  = threadIdx.x & 15;
    if (node >= N_NODES) return;
    const float* hr = h + (size_t)node * NHID;
    float sum = 0.f;
#pragma unroll 8
    for (int k = 0; k < NHID; ++k)
        sum = fmaf(hr[k], W2[k * NCLASS + col], sum);
    s2[(size_t)node * NCLASS + col] = sum;
}

__global__ void spmm2_kernel(const int* __restrict__ src, const int* __restrict__ dst,
                             const float* __restrict__ w, const float* __restrict__ s2,
                             float* __restrict__ out) {
    int e = blockIdx.x * 16 + (threadIdx.x >> 4);
    if (e >= N_EDGES) return;
    int lane = threadIdx.x & 15;
    int s = min(max(src[e], 0), N_NODES - 1);
    int d = min(max(dst[e], 0), N_NODES - 1);
    float v = w[e] * s2[(size_t)s * NCLASS + lane];
    atomicAdd(&out[(size_t)d * NCLASS + lane], v);
}

__global__ void logsoftmax_kernel(float* __restrict__ out, const float* __restrict__ b2) {
    int n = blockIdx.x * 256 + threadIdx.x;
    if (n >= N_NODES) return;
    float v[NCLASS];
    float mx = -INFINITY;
#pragma unroll
    for (int c = 0; c < NCLASS; ++c) {
        v[c] = out[(size_t)n * NCLASS + c] + b2[c];
        mx = fmaxf(mx, v[c]);
    }
    float ssum = 0.f;
#pragma unroll
    for (int c = 0; c < NCLASS; ++c) ssum += expf(v[c] - mx);
    float ls = mx + logf(ssum);
#pragma unroll
    for (int c = 0; c < NCLASS; ++c) out[(size_t)n * NCLASS + c] = v[c] - ls;
}

// ======================= launch ============================================

extern "C" void kernel_launch(void* const* d_in, const int* in_sizes, int n_in,
                              void* d_out, int out_size, void* d_ws, size_t ws_size,
                              hipStream_t stream) {
    if (n_in != 8) return;
    const int expected[8] = { N_NODES * NFEAT, NFEAT * NHID, NHID,
                              NHID * NCLASS, NCLASS, N_EDGES, N_EDGES, N_EDGES };
    for (int i = 0; i < 8; ++i)
        if (in_sizes[i] != expected[i]) return;
    if (out_size != N_NODES * NCLASS) return;

    const float* x  = (const float*)d_in[0];
    const float* W1 = (const float*)d_in[1];
    const float* b1 = (const float*)d_in[2];
    const float* W2 = (const float*)d_in[3];
    const float* b2 = (const float*)d_in[4];
    const int* edge_src = (const int*)d_in[5];
    const int* edge_dst = (const int*)d_in[6];
    const float* edge_w = (const float*)d_in[7];
    float* out = (float*)d_out;

    const size_t S1_ELTS = (size_t)N_NODES * NHID;          // 3.2M (ushorts)
    const size_t CAP_WORDS = (size_t)NBINS * BIN_CAP * 2;   // int2 region, words
    // layout (32-bit words) — fully DISJOINT (s1b live alongside csr_bin
    // inside sort_spmm1_fused):
    //   [0, CAP)          csr_bin    (16 MB)
    //   [CAP, 2CAP)       csr_edge   (16 MB)
    //   [2CAP, +2N)       row_range  (0.4 MB)
    //   [.., +512)        bin_cursor (391 ints + pad, keeps s1b 16B-aligned)
    //   [.., +S1/2)       s1b        (6.4 MB bf16)
    //   [.., +N*NCLASS)   s2         (3.2 MB fp32)
    const size_t NEW_WORDS = 2 * CAP_WORDS + 2 * (size_t)N_NODES + 512
                           + S1_ELTS / 2 + (size_t)N_NODES * NCLASS;
    if (ws_size >= NEW_WORDS * 4) {
        int2*  csr_bin    = (int2*)d_ws;
        int2*  csr_edge   = (int2*)((int*)d_ws + CAP_WORDS);
        int2*  row_range  = (int2*)((int*)d_ws + 2 * CAP_WORDS);
        int*   bin_cursor = (int*)d_ws + 2 * CAP_WORDS + 2 * (size_t)N_NODES;
        unsigned short* s1b =
            (unsigned short*)((int*)d_ws + 2 * CAP_WORDS + 2 * (size_t)N_NODES + 512);
        float* s2 = (float*)d_ws + 2 * CAP_WORDS + 2 * (size_t)N_NODES + 512
                  + S1_ELTS / 2;

        // gemm1 first: its block 0 zeroes bin_cursor (replaces memset dispatch)
        gemm1_mfma<<<(N_NODES + 63) / 64, 256, 0, stream>>>(x, W1, s1b, bin_cursor);
        bin_scatter_kernel<<<K3_BLOCKS, K3_THREADS, 0, stream>>>(
            edge_src, edge_dst, edge_w, bin_cursor, csr_bin);
        sort_spmm1_fused<<<NBINS, 1024, 0, stream>>>(
            bin_cursor, csr_bin, csr_edge, row_range,
            (const uint4*)s1b, b1, W2, s2);
        spmm2_csr_kernel<<<(N_NODES + 15) / 16, 256, 0, stream>>>(
            row_range, csr_edge, s2, b2, out);
        return;
    }

    // --- fallback: proven atomic path (25.6 MB ws) ---
    if (ws_size < 2 * S1_ELTS * sizeof(float)) return;
    float* s1 = (float*)d_ws;
    float* h  = s1 + S1_ELTS;
    float* s2 = s1;
    zero_kernel<<<(N_NODES * NHID + 255) / 256, 256, 0, stream>>>(h, out);
    gemm1_kernel<<<(N_NODES + 3) / 4, 256, 0, stream>>>(x, W1, s1);
    spmm1_kernel<<<(N_EDGES + 3) / 4, 256, 0, stream>>>(edge_src, edge_dst, edge_w, s1, h);
    bias_relu_kernel<<<(N_NODES * NHID + 255) / 256, 256, 0, stream>>>(h, b1);
    gemm2_kernel<<<(N_NODES + 15) / 16, 256, 0, stream>>>(h, W2, s2);
    spmm2_kernel<<<(N_EDGES + 15) / 16, 256, 0, stream>>>(edge_src, edge_dst, edge_w, s2, out);
    logsoftmax_kernel<<<(N_NODES + 255) / 256, 256, 0, stream>>>(out, b2);
}